// Round 23
// baseline (130.272 us; speedup 1.0000x reference)
//
#include <hip/hip_runtime.h>
#include <math.h>

#define NPTS 262144
#define KC 512
#define DD 64
#define MARGIN 0.02f
#define SHIFT 32.0f
#define SENTINEL -1.0f
#define CSTRIDE 68            // f32 row stride in LDS for rescore (272B, 16B-aligned)
#define ABLOCK 512            // approx block: 8 waves
#define TILES 2               // 256-point tiles per approx block

typedef _Float16 f16x8 __attribute__((ext_vector_type(8)));
typedef _Float16 f16x4 __attribute__((ext_vector_type(4)));
typedef float f32x4 __attribute__((ext_vector_type(4)));

__device__ __forceinline__ float csq_pairwise8(const float* row) {
    float r[8];
#pragma unroll
    for (int t = 0; t < 8; ++t) r[t] = __fmul_rn(row[t], row[t]);
#pragma unroll
    for (int b = 1; b < 8; ++b)
#pragma unroll
        for (int t = 0; t < 8; ++t)
            r[t] = __fadd_rn(r[t], __fmul_rn(row[8 * b + t], row[8 * b + t]));
    return __fadd_rn(__fadd_rn(__fadd_rn(r[0], r[1]), __fadd_rn(r[2], r[3])),
                     __fadd_rn(__fadd_rn(r[4], r[5]), __fadd_rn(r[6], r[7])));
}

// Self-prepping approx (R22, byte-identical -- passing, clean).
__global__ __launch_bounds__(ABLOCK) void approx_kernel(const float* __restrict__ x,
                                                        const float* __restrict__ c,
                                                        float* __restrict__ out_assign) {
    extern __shared__ char smem[];          // [0,64K): swizzled c_f16 | [64K,66K): scs
    float* scs = (float*)(smem + 65536);    // 512 f32: csq_approx + SHIFT

    int tid = threadIdx.x;
    const float4* src = (const float4*)c;
#pragma unroll
    for (int i = 0; i < 16; ++i) {          // 16 x 512 = 8192 f32x4 chunks = 512 rows
        int chunk = tid + i * ABLOCK;
        int row = chunk >> 4, q = chunk & 15;
        float4 v = src[chunk];
        f16x4 h;
        h[0] = (_Float16)v.x; h[1] = (_Float16)v.y;
        h[2] = (_Float16)v.z; h[3] = (_Float16)v.w;
        int off = row * 128 + (((q >> 1) ^ (row & 7)) << 4) + (q & 1) * 8;
        *(f16x4*)(smem + off) = h;
        float s = (v.x * v.x + v.y * v.y) + (v.z * v.z + v.w * v.w);
#pragma unroll
        for (int m = 1; m < 16; m <<= 1) s += __shfl_xor(s, m);
        if (q == 0) scs[row] = s + SHIFT;
    }

    int wid = tid >> 6, lane = tid & 63;
    int lrow = lane & 15, lgrp = lane >> 4;

    for (int tile = 0; tile < TILES; ++tile) {
        __syncthreads();
        int pbase = (blockIdx.x * TILES + tile) * 256 + wid * 32;

        f16x8 a[2][2];
#pragma unroll
        for (int s = 0; s < 2; ++s)
#pragma unroll
            for (int kk = 0; kk < 2; ++kk) {
                const float4* p = (const float4*)(x + (size_t)(pbase + s * 16 + lrow) * DD
                                                  + kk * 32 + lgrp * 8);
                float4 u0 = p[0], u1 = p[1];
                f16x8 t;
                t[0] = (_Float16)u0.x; t[1] = (_Float16)u0.y;
                t[2] = (_Float16)u0.z; t[3] = (_Float16)u0.w;
                t[4] = (_Float16)u1.x; t[5] = (_Float16)u1.y;
                t[6] = (_Float16)u1.z; t[7] = (_Float16)u1.w;
                a[s][kk] = t;
            }

        unsigned b1[2][4], b2[2][4];
#pragma unroll
        for (int s = 0; s < 2; ++s)
#pragma unroll
            for (int r = 0; r < 4; ++r) { b1[s][r] = 0xFFFFFFFFu; b2[s][r] = 0xFFFFFFFFu; }

        int base0 = lrow * 128 + ((lgrp ^ (lane & 7)) << 4);
        int base1 = base0 ^ 64;
        int centv = lrow;

        f16x8 nb0 = *(const f16x8*)(smem + base0);
        f16x8 nb1 = *(const f16x8*)(smem + base1);

        for (int ct = 0; ct < 32; ++ct) {
            f16x8 bk0 = nb0, bk1 = nb1;
            base0 += 2048; base1 += 2048;
            nb0 = *(const f16x8*)(smem + base0);
            nb1 = *(const f16x8*)(smem + base1);
            float cs = scs[centv];
            int kv = centv;
            centv += 16;

            f32x4 z = {0.f, 0.f, 0.f, 0.f};
            f32x4 p0a = __builtin_amdgcn_mfma_f32_16x16x32_f16(a[0][0], bk0, z, 0, 0, 0);
            f32x4 p0b = __builtin_amdgcn_mfma_f32_16x16x32_f16(a[0][1], bk1, z, 0, 0, 0);
            f32x4 p1a = __builtin_amdgcn_mfma_f32_16x16x32_f16(a[1][0], bk0, z, 0, 0, 0);
            f32x4 p1b = __builtin_amdgcn_mfma_f32_16x16x32_f16(a[1][1], bk1, z, 0, 0, 0);
#pragma unroll
            for (int r = 0; r < 4; ++r) {
                float d0 = __builtin_fmaf(-2.0f, __fadd_rn(p0a[r], p0b[r]), cs);
                float d1 = __builtin_fmaf(-2.0f, __fadd_rn(p1a[r], p1b[r]), cs);
                unsigned k0 = (__float_as_uint(d0) & 0xFFFFFE00u) | (unsigned)kv;
                unsigned k1 = (__float_as_uint(d1) & 0xFFFFFE00u) | (unsigned)kv;
                unsigned m0 = max(b1[0][r], k0);
                b1[0][r] = min(b1[0][r], k0);
                b2[0][r] = min(b2[0][r], m0);
                unsigned m1 = max(b1[1][r], k1);
                b1[1][r] = min(b1[1][r], k1);
                b2[1][r] = min(b2[1][r], m1);
            }
        }

#pragma unroll
        for (int d = 1; d < 16; d <<= 1) {
#pragma unroll
            for (int s = 0; s < 2; ++s)
#pragma unroll
                for (int r = 0; r < 4; ++r) {
                    unsigned o1 = (unsigned)__shfl_xor((int)b1[s][r], d);
                    unsigned o2 = (unsigned)__shfl_xor((int)b2[s][r], d);
                    unsigned mx = max(b1[s][r], o1);
                    b1[s][r] = min(b1[s][r], o1);
                    b2[s][r] = min(min(b2[s][r], o2), mx);
                }
        }

        if (lrow == 0) {
#pragma unroll
            for (int s = 0; s < 2; ++s)
#pragma unroll
                for (int r = 0; r < 4; ++r) {
                    int p = pbase + s * 16 + lgrp * 4 + r;
                    unsigned w = b1[s][r];
                    float d1 = __uint_as_float(w & 0xFFFFFE00u);
                    float d2 = __uint_as_float(b2[s][r] & 0xFFFFFE00u);
                    float kf = (float)(w & 0x1FFu);
                    out_assign[p] = (d2 - d1 <= MARGIN) ? SENTINEL : kf;
                }
        }
    }
}

// Rescore with CONFLICT-FREE LDS layout. R22's PMC: 1.57M bank conflicts --
// lane l reads row k=j*64+l, and 68*l = 4l (mod 32), so lanes {l, l+8, ...}
// hit the same 4-bank slot at different addresses = 8-way serialize per
// ds_read_b128. Fix (T2): store chunk q of row at physical slot q^((row>>3)&7);
// read side swizzle key = (lane>>3)&7 (j-independent). Bank start becomes
// 4(lane&7)+4(q^b): the 8 aliasing lanes spread over 8 distinct slots.
// Logical-q iteration order unchanged -> dot product bit-identical. scsq is
// computed from GLOBAL c (LDS rows are permuted) with the R13-R20-proven
// per-thread csq_pairwise8 -- identical op sequence, absmax=0 pedigree.
__global__ __launch_bounds__(256) void rescore_kernel(const float* __restrict__ x,
                                                      const float* __restrict__ c,
                                                      float* __restrict__ out_c,
                                                      float* __restrict__ out_assign) {
    extern __shared__ char rsm[];
    float* cs = (float*)rsm;                       // [512][68] f32, chunk-swizzled
    float* scsq = (float*)(rsm + KC * CSTRIDE * 4);// 512 f32, exact np csq

    int tid = threadIdx.x;
#pragma unroll
    for (int it = 0; it < 32; ++it) {
        int idx = tid + it * 256;                  // 8192 float4 chunks
        int row = idx >> 4, q = idx & 15;
        float4 v = ((const float4*)(c + row * DD))[q];
        int qs = q ^ ((row >> 3) & 7);             // swizzled 16B slot
        float* d = &cs[row * CSTRIDE + (qs << 2)];
        d[0] = v.x; d[1] = v.y; d[2] = v.z; d[3] = v.w;
    }
    // Centroid passthrough: block b copies 32 float4s (threads 0..31).
    if (tid < 32) {
        int j = blockIdx.x * 32 + tid;             // 8192 float4s total
        ((float4*)out_c)[j] = ((const float4*)c)[j];
    }
    // Exact csq from GLOBAL c (np pairwise-8 order; R13-R20-proven pattern).
    scsq[tid] = csq_pairwise8(c + (size_t)tid * DD);
    scsq[tid + 256] = csq_pairwise8(c + (size_t)(tid + 256) * DD);
    __syncthreads();

    int wid = tid >> 6, lane = tid & 63;
    int sw = (lane >> 3) & 7;                      // read-side swizzle key
    int range = blockIdx.x * 1024 + wid * 256;     // this wave's 256 points

    for (int seg = 0; seg < 4; ++seg) {
        int wbase = range + seg * 64;
        float v = out_assign[wbase + lane];
        unsigned long long mask = __ballot(v < 0.0f);

        while (mask) {
            int bit0 = __ffsll((long long)mask) - 1;
            mask &= mask - 1;
            int bit1 = bit0;
            if (mask) {                            // pair two flagged points
                bit1 = __ffsll((long long)mask) - 1;
                mask &= mask - 1;
            }
            int iA = wbase + bit0;
            int iB = wbase + bit1;
            const float* xA = x + (size_t)iA * DD; // wave-uniform -> s_loads
            const float* xB = x + (size_t)iB * DD;
            float xsqA = csq_pairwise8(xA);
            float xsqB = csq_pairwise8(xB);

            unsigned long long bA = ~0ull, bB = ~0ull;
#pragma unroll 1
            for (int j = 0; j < 8; ++j) {
                int k = j * 64 + lane;
                const float* crow = &cs[k * CSTRIDE];
                float a0 = 0.f, a1 = 0.f, a2 = 0.f, a3 = 0.f;
                float c0 = 0.f, c1 = 0.f, c2 = 0.f, c3 = 0.f;
#pragma unroll
                for (int q = 0; q < 16; ++q) {     // logical q order (bit-exact)
                    float4 cq = *(const float4*)(crow + ((q ^ sw) << 2));
                    a0 = __fmaf_rn(xA[4 * q + 0], cq.x, a0);
                    a1 = __fmaf_rn(xA[4 * q + 1], cq.y, a1);
                    a2 = __fmaf_rn(xA[4 * q + 2], cq.z, a2);
                    a3 = __fmaf_rn(xA[4 * q + 3], cq.w, a3);
                    c0 = __fmaf_rn(xB[4 * q + 0], cq.x, c0);
                    c1 = __fmaf_rn(xB[4 * q + 1], cq.y, c1);
                    c2 = __fmaf_rn(xB[4 * q + 2], cq.z, c2);
                    c3 = __fmaf_rn(xB[4 * q + 3], cq.w, c3);
                }
                float sq = scsq[k];
                float accA = __fadd_rn(__fadd_rn(a0, a1), __fadd_rn(a2, a3));
                float accB = __fadd_rn(__fadd_rn(c0, c1), __fadd_rn(c2, c3));
                float dA = __fmaf_rn(-2.0f, accA, __fadd_rn(xsqA, sq));
                float dB = __fmaf_rn(-2.0f, accB, __fadd_rn(xsqB, sq));
                unsigned long long kA =
                    ((unsigned long long)__float_as_uint(dA) << 32) | (unsigned)k;
                unsigned long long kB =
                    ((unsigned long long)__float_as_uint(dB) << 32) | (unsigned)k;
                bA = bA < kA ? bA : kA;
                bB = bB < kB ? bB : kB;
            }
#pragma unroll
            for (int dd = 1; dd < 64; dd <<= 1) {
                unsigned hiA = (unsigned)__shfl_xor((int)(bA >> 32), dd);
                unsigned loA = (unsigned)__shfl_xor((int)(bA & 0xFFFFFFFFull), dd);
                unsigned long long oA = ((unsigned long long)hiA << 32) | loA;
                bA = bA < oA ? bA : oA;
                unsigned hiB = (unsigned)__shfl_xor((int)(bB >> 32), dd);
                unsigned loB = (unsigned)__shfl_xor((int)(bB & 0xFFFFFFFFull), dd);
                unsigned long long oB = ((unsigned long long)hiB << 32) | loB;
                bB = bB < oB ? bB : oB;
            }
            if (lane == 0) {
                out_assign[iA] = (float)(unsigned)(bA & 0xFFFFFFFFull);
                out_assign[iB] = (float)(unsigned)(bB & 0xFFFFFFFFull);
            }
        }
    }
}

extern "C" void kernel_launch(void* const* d_in, const int* in_sizes, int n_in,
                              void* d_out, int out_size, void* d_ws, size_t ws_size,
                              hipStream_t stream) {
    const float* x = (const float*)d_in[0];
    const float* c = (const float*)d_in[1];
    float* out = (float*)d_out;
    float* out_assign = out + KC * DD;

    approx_kernel<<<NPTS / (256 * TILES), ABLOCK, 67584, stream>>>(x, c, out_assign);
    rescore_kernel<<<256, 256, KC * CSTRIDE * 4 + 2048, stream>>>(x, c, out,
                                                                  out_assign);
}

// Round 24
// 91.649 us; speedup vs baseline: 1.4214x; 1.4214x over previous
//
#include <hip/hip_runtime.h>
#include <math.h>

#define NPTS 262144
#define KC 512
#define DD 64
#define MARGIN 0.02f
#define SHIFT 32.0f
#define CSTRIDE 68            // f32 row stride in LDS for rescore (272B)
#define ABLOCK 512            // approx block: 8 waves
#define TILES 2               // 256-point tiles per approx block

typedef _Float16 f16x8 __attribute__((ext_vector_type(8)));
typedef _Float16 f16x4 __attribute__((ext_vector_type(4)));
typedef float f32x4 __attribute__((ext_vector_type(4)));

__device__ __forceinline__ float csq_pairwise8(const float* row) {
    float r[8];
#pragma unroll
    for (int t = 0; t < 8; ++t) r[t] = __fmul_rn(row[t], row[t]);
#pragma unroll
    for (int b = 1; b < 8; ++b)
#pragma unroll
        for (int t = 0; t < 8; ++t)
            r[t] = __fadd_rn(r[t], __fmul_rn(row[8 * b + t], row[8 * b + t]));
    return __fadd_rn(__fadd_rn(__fadd_rn(r[0], r[1]), __fadd_rn(r[2], r[3])),
                     __fadd_rn(__fadd_rn(r[4], r[5]), __fadd_rn(r[6], r[7])));
}

// Sorted-triple insert: 6 min/max, keeps b1<=b2<=b3 = smallest 3 keys.
#define UPD3(b1v, b2v, b3v, dv)                                     \
    {                                                               \
        unsigned key_ = (__float_as_uint(dv) & 0xFFFFFE00u) | (unsigned)kv; \
        unsigned m1_ = min(b1v, key_), M1_ = max(b1v, key_);        \
        unsigned m2_ = min(b2v, M1_), M2_ = max(b2v, M1_);          \
        b3v = min(b3v, M2_); b2v = m2_; b1v = m1_;                  \
    }

// Merge two sorted triples (mine, other-lane's), keep smallest 3.
#define MRG3(b1v, b2v, b3v)                                         \
    {                                                               \
        unsigned o1_ = (unsigned)__shfl_xor((int)b1v, d);           \
        unsigned o2_ = (unsigned)__shfl_xor((int)b2v, d);           \
        unsigned o3_ = (unsigned)__shfl_xor((int)b3v, d);           \
        unsigned A_ = max(b1v, o1_);                                \
        unsigned t_ = min(b2v, o2_);                                \
        b1v = min(b1v, o1_);                                        \
        unsigned c2_ = min(A_, t_);                                 \
        b3v = min(min(max(A_, t_), max(b2v, o2_)), min(b3v, o3_));  \
        b2v = c2_;                                                  \
    }

// Approx with BEST-3 tracking. Output encoding per point:
//   gap3 <= M  -> -1            (full rescore: argmin could be beyond top-2)
//   gap2 <= M  -> -(2+k1*1024+k2) (exact argmin provably in {k1,k2})
//   else       -> k1            (certain)
// Candidate-set argument: any k with exact d_k <= exact d_k1 satisfies
// d'_k <= d'_1 + 2E + q <= d'_1 + M, so gap3 > M => candidates in {k1,k2}.
__global__ __launch_bounds__(ABLOCK) void approx_kernel(const float* __restrict__ x,
                                                        const float* __restrict__ c,
                                                        float* __restrict__ out_assign) {
    extern __shared__ char smem[];          // [0,64K): swizzled c_f16 | [64K,66K): scs
    float* scs = (float*)(smem + 65536);    // 512 f32: csq_approx + SHIFT

    int tid = threadIdx.x;
    const float4* src = (const float4*)c;
#pragma unroll
    for (int i = 0; i < 16; ++i) {          // 8192 f32x4 chunks = all 512 rows
        int chunk = tid + i * ABLOCK;
        int row = chunk >> 4, q = chunk & 15;
        float4 v = src[chunk];
        f16x4 h;
        h[0] = (_Float16)v.x; h[1] = (_Float16)v.y;
        h[2] = (_Float16)v.z; h[3] = (_Float16)v.w;
        int off = row * 128 + (((q >> 1) ^ (row & 7)) << 4) + (q & 1) * 8;
        *(f16x4*)(smem + off) = h;
        float s = (v.x * v.x + v.y * v.y) + (v.z * v.z + v.w * v.w);
#pragma unroll
        for (int m = 1; m < 16; m <<= 1) s += __shfl_xor(s, m);
        if (q == 0) scs[row] = s + SHIFT;
    }

    int wid = tid >> 6, lane = tid & 63;
    int lrow = lane & 15, lgrp = lane >> 4;

    for (int tile = 0; tile < TILES; ++tile) {
        __syncthreads();
        int pbase = (blockIdx.x * TILES + tile) * 256 + wid * 32;

        f16x8 a[2][2];
#pragma unroll
        for (int s = 0; s < 2; ++s)
#pragma unroll
            for (int kk = 0; kk < 2; ++kk) {
                const float4* p = (const float4*)(x + (size_t)(pbase + s * 16 + lrow) * DD
                                                  + kk * 32 + lgrp * 8);
                float4 u0 = p[0], u1 = p[1];
                f16x8 t;
                t[0] = (_Float16)u0.x; t[1] = (_Float16)u0.y;
                t[2] = (_Float16)u0.z; t[3] = (_Float16)u0.w;
                t[4] = (_Float16)u1.x; t[5] = (_Float16)u1.y;
                t[6] = (_Float16)u1.z; t[7] = (_Float16)u1.w;
                a[s][kk] = t;
            }

        unsigned b1[2][4], b2[2][4], b3[2][4];
#pragma unroll
        for (int s = 0; s < 2; ++s)
#pragma unroll
            for (int r = 0; r < 4; ++r) {
                b1[s][r] = 0xFFFFFFFFu; b2[s][r] = 0xFFFFFFFFu; b3[s][r] = 0xFFFFFFFFu;
            }

        int base0 = lrow * 128 + ((lgrp ^ (lane & 7)) << 4);
        int base1 = base0 ^ 64;
        int centv = lrow;

        f16x8 nb0 = *(const f16x8*)(smem + base0);
        f16x8 nb1 = *(const f16x8*)(smem + base1);

        for (int ct = 0; ct < 32; ++ct) {
            f16x8 bk0 = nb0, bk1 = nb1;
            base0 += 2048; base1 += 2048;
            nb0 = *(const f16x8*)(smem + base0);   // final read lands in scs: in-bounds
            nb1 = *(const f16x8*)(smem + base1);
            float cs = scs[centv];
            int kv = centv;
            centv += 16;

            f32x4 z = {0.f, 0.f, 0.f, 0.f};
            f32x4 p0a = __builtin_amdgcn_mfma_f32_16x16x32_f16(a[0][0], bk0, z, 0, 0, 0);
            f32x4 p0b = __builtin_amdgcn_mfma_f32_16x16x32_f16(a[0][1], bk1, z, 0, 0, 0);
            f32x4 p1a = __builtin_amdgcn_mfma_f32_16x16x32_f16(a[1][0], bk0, z, 0, 0, 0);
            f32x4 p1b = __builtin_amdgcn_mfma_f32_16x16x32_f16(a[1][1], bk1, z, 0, 0, 0);
#pragma unroll
            for (int r = 0; r < 4; ++r) {
                float d0 = __builtin_fmaf(-2.0f, __fadd_rn(p0a[r], p0b[r]), cs);
                float d1 = __builtin_fmaf(-2.0f, __fadd_rn(p1a[r], p1b[r]), cs);
                UPD3(b1[0][r], b2[0][r], b3[0][r], d0)
                UPD3(b1[1][r], b2[1][r], b3[1][r], d1)
            }
        }

#pragma unroll
        for (int d = 1; d < 16; d <<= 1) {
#pragma unroll
            for (int s = 0; s < 2; ++s)
#pragma unroll
                for (int r = 0; r < 4; ++r) {
                    MRG3(b1[s][r], b2[s][r], b3[s][r])
                }
        }

        if (lrow == 0) {
#pragma unroll
            for (int s = 0; s < 2; ++s)
#pragma unroll
                for (int r = 0; r < 4; ++r) {
                    int p = pbase + s * 16 + lgrp * 4 + r;
                    unsigned w1 = b1[s][r], w2 = b2[s][r], w3 = b3[s][r];
                    float d1 = __uint_as_float(w1 & 0xFFFFFE00u);
                    float d2 = __uint_as_float(w2 & 0xFFFFFE00u);
                    float d3 = __uint_as_float(w3 & 0xFFFFFE00u);
                    int k1 = (int)(w1 & 0x1FFu), k2 = (int)(w2 & 0x1FFu);
                    float res;
                    if (d3 - d1 <= MARGIN) res = -1.0f;
                    else if (d2 - d1 <= MARGIN) res = -(float)(2 + k1 * 1024 + k2);
                    else res = (float)k1;
                    out_assign[p] = res;
                }
        }
    }
}

// Rescore v2 (R22 LDS layout -- unswizzled; R23's swizzle measured WORSE):
// lane-parallel exact pair-compare for 2-candidate points, wave-paired full
// rescan for -1 points. All distance math = bit-exact np-replica op order.
__global__ __launch_bounds__(256) void rescore_kernel(const float* __restrict__ x,
                                                      const float* __restrict__ c,
                                                      float* __restrict__ out_c,
                                                      float* __restrict__ out_assign) {
    extern __shared__ char rsm[];
    float* cs = (float*)rsm;                       // [512][68] f32
    float* scsq = (float*)(rsm + KC * CSTRIDE * 4);// 512 f32, exact np csq

    int tid = threadIdx.x;
#pragma unroll
    for (int it = 0; it < 32; ++it) {
        int idx = tid + it * 256;                  // 8192 float4 chunks
        int row = idx >> 4, q = idx & 15;
        float4 v = ((const float4*)(c + row * DD))[q];
        float* d = &cs[row * CSTRIDE + q * 4];
        d[0] = v.x; d[1] = v.y; d[2] = v.z; d[3] = v.w;
    }
    if (tid < 32) {
        int j = blockIdx.x * 32 + tid;             // centroid passthrough
        ((float4*)out_c)[j] = ((const float4*)c)[j];
    }
    __syncthreads();
    scsq[tid] = csq_pairwise8(&cs[tid * CSTRIDE]);
    scsq[tid + 256] = csq_pairwise8(&cs[(tid + 256) * CSTRIDE]);
    __syncthreads();

    int wid = tid >> 6, lane = tid & 63;
    int range = blockIdx.x * 1024 + wid * 256;

    for (int seg = 0; seg < 4; ++seg) {
        int wbase = range + seg * 64;
        int myp = wbase + lane;
        float v = out_assign[myp];

        // Lane-parallel 2-candidate resolve (v <= -2).
        if (v < -1.5f) {
            int m = (int)(-v) - 2;
            int ka = m >> 10, kb = m & 1023;
            int klo = ka < kb ? ka : kb;
            int khi = ka < kb ? kb : ka;
            const float4* xp = (const float4*)(x + (size_t)myp * DD);
            const float* rlo = &cs[klo * CSTRIDE];
            const float* rhi = &cs[khi * CSTRIDE];
            float r8[8];
            float a0 = 0.f, a1 = 0.f, a2 = 0.f, a3 = 0.f;
            float c0 = 0.f, c1 = 0.f, c2 = 0.f, c3 = 0.f;
#pragma unroll
            for (int q = 0; q < 16; ++q) {
                float4 xq = xp[q];
                float4 ql = *(const float4*)(rlo + q * 4);
                float4 qh = *(const float4*)(rhi + q * 4);
                int t0 = (q & 1) * 4;
                if (q < 2) {                       // b=0: init r8 (np order)
                    r8[t0 + 0] = __fmul_rn(xq.x, xq.x);
                    r8[t0 + 1] = __fmul_rn(xq.y, xq.y);
                    r8[t0 + 2] = __fmul_rn(xq.z, xq.z);
                    r8[t0 + 3] = __fmul_rn(xq.w, xq.w);
                } else {
                    r8[t0 + 0] = __fadd_rn(r8[t0 + 0], __fmul_rn(xq.x, xq.x));
                    r8[t0 + 1] = __fadd_rn(r8[t0 + 1], __fmul_rn(xq.y, xq.y));
                    r8[t0 + 2] = __fadd_rn(r8[t0 + 2], __fmul_rn(xq.z, xq.z));
                    r8[t0 + 3] = __fadd_rn(r8[t0 + 3], __fmul_rn(xq.w, xq.w));
                }
                a0 = __fmaf_rn(xq.x, ql.x, a0);
                a1 = __fmaf_rn(xq.y, ql.y, a1);
                a2 = __fmaf_rn(xq.z, ql.z, a2);
                a3 = __fmaf_rn(xq.w, ql.w, a3);
                c0 = __fmaf_rn(xq.x, qh.x, c0);
                c1 = __fmaf_rn(xq.y, qh.y, c1);
                c2 = __fmaf_rn(xq.z, qh.z, c2);
                c3 = __fmaf_rn(xq.w, qh.w, c3);
            }
            float x_sq = __fadd_rn(__fadd_rn(__fadd_rn(r8[0], r8[1]), __fadd_rn(r8[2], r8[3])),
                                   __fadd_rn(__fadd_rn(r8[4], r8[5]), __fadd_rn(r8[6], r8[7])));
            float dlo = __fmaf_rn(-2.0f, __fadd_rn(__fadd_rn(a0, a1), __fadd_rn(a2, a3)),
                                  __fadd_rn(x_sq, scsq[klo]));
            float dhi = __fmaf_rn(-2.0f, __fadd_rn(__fadd_rn(c0, c1), __fadd_rn(c2, c3)),
                                  __fadd_rn(x_sq, scsq[khi]));
            int ans = (dhi < dlo) ? khi : klo;     // strict <: lower index wins ties
            out_assign[myp] = (float)ans;
        }

        // Wave-paired full rescan for -1 points.
        unsigned long long mask = __ballot(v > -1.5f && v < -0.5f);
        while (mask) {
            int bit0 = __ffsll((long long)mask) - 1;
            mask &= mask - 1;
            int bit1 = bit0;
            if (mask) {
                bit1 = __ffsll((long long)mask) - 1;
                mask &= mask - 1;
            }
            int iA = wbase + bit0;
            int iB = wbase + bit1;
            const float* xA = x + (size_t)iA * DD; // wave-uniform -> s_loads
            const float* xB = x + (size_t)iB * DD;
            float xsqA = csq_pairwise8(xA);
            float xsqB = csq_pairwise8(xB);

            unsigned long long bA = ~0ull, bB = ~0ull;
#pragma unroll 1
            for (int j = 0; j < 8; ++j) {
                int k = j * 64 + lane;
                const float* crow = &cs[k * CSTRIDE];
                float a0 = 0.f, a1 = 0.f, a2 = 0.f, a3 = 0.f;
                float c0 = 0.f, c1 = 0.f, c2 = 0.f, c3 = 0.f;
#pragma unroll
                for (int q = 0; q < 16; ++q) {
                    float4 cq = *(const float4*)(crow + q * 4);
                    a0 = __fmaf_rn(xA[4 * q + 0], cq.x, a0);
                    a1 = __fmaf_rn(xA[4 * q + 1], cq.y, a1);
                    a2 = __fmaf_rn(xA[4 * q + 2], cq.z, a2);
                    a3 = __fmaf_rn(xA[4 * q + 3], cq.w, a3);
                    c0 = __fmaf_rn(xB[4 * q + 0], cq.x, c0);
                    c1 = __fmaf_rn(xB[4 * q + 1], cq.y, c1);
                    c2 = __fmaf_rn(xB[4 * q + 2], cq.z, c2);
                    c3 = __fmaf_rn(xB[4 * q + 3], cq.w, c3);
                }
                float sq = scsq[k];
                float accA = __fadd_rn(__fadd_rn(a0, a1), __fadd_rn(a2, a3));
                float accB = __fadd_rn(__fadd_rn(c0, c1), __fadd_rn(c2, c3));
                float dA = __fmaf_rn(-2.0f, accA, __fadd_rn(xsqA, sq));
                float dB = __fmaf_rn(-2.0f, accB, __fadd_rn(xsqB, sq));
                unsigned long long kA =
                    ((unsigned long long)__float_as_uint(dA) << 32) | (unsigned)k;
                unsigned long long kB =
                    ((unsigned long long)__float_as_uint(dB) << 32) | (unsigned)k;
                bA = bA < kA ? bA : kA;
                bB = bB < kB ? bB : kB;
            }
#pragma unroll
            for (int dd = 1; dd < 64; dd <<= 1) {
                unsigned hiA = (unsigned)__shfl_xor((int)(bA >> 32), dd);
                unsigned loA = (unsigned)__shfl_xor((int)(bA & 0xFFFFFFFFull), dd);
                unsigned long long oA = ((unsigned long long)hiA << 32) | loA;
                bA = bA < oA ? bA : oA;
                unsigned hiB = (unsigned)__shfl_xor((int)(bB >> 32), dd);
                unsigned loB = (unsigned)__shfl_xor((int)(bB & 0xFFFFFFFFull), dd);
                unsigned long long oB = ((unsigned long long)hiB << 32) | loB;
                bB = bB < oB ? bB : oB;
            }
            if (lane == 0) {
                out_assign[iA] = (float)(unsigned)(bA & 0xFFFFFFFFull);
                out_assign[iB] = (float)(unsigned)(bB & 0xFFFFFFFFull);
            }
        }
    }
}

extern "C" void kernel_launch(void* const* d_in, const int* in_sizes, int n_in,
                              void* d_out, int out_size, void* d_ws, size_t ws_size,
                              hipStream_t stream) {
    const float* x = (const float*)d_in[0];
    const float* c = (const float*)d_in[1];
    float* out = (float*)d_out;
    float* out_assign = out + KC * DD;

    approx_kernel<<<NPTS / (256 * TILES), ABLOCK, 67584, stream>>>(x, c, out_assign);
    rescore_kernel<<<256, 256, KC * CSTRIDE * 4 + 2048, stream>>>(x, c, out,
                                                                  out_assign);
}

// Round 25
// 80.610 us; speedup vs baseline: 1.6161x; 1.1370x over previous
//
#include <hip/hip_runtime.h>
#include <math.h>

#define NPTS 262144
#define KC 512
#define DD 64
#define MARGIN 0.02f
#define SHIFT 32.0f
#define CSTRIDE 68            // f32 row stride in LDS for rescore (272B)
#define ABLOCK 512            // approx block: 8 waves
#define TILES 2               // 256-point tiles per approx block

typedef _Float16 f16x8 __attribute__((ext_vector_type(8)));
typedef _Float16 f16x4 __attribute__((ext_vector_type(4)));
typedef float f32x4 __attribute__((ext_vector_type(4)));

__device__ __forceinline__ float csq_pairwise8(const float* row) {
    float r[8];
#pragma unroll
    for (int t = 0; t < 8; ++t) r[t] = __fmul_rn(row[t], row[t]);
#pragma unroll
    for (int b = 1; b < 8; ++b)
#pragma unroll
        for (int t = 0; t < 8; ++t)
            r[t] = __fadd_rn(r[t], __fmul_rn(row[8 * b + t], row[8 * b + t]));
    return __fadd_rn(__fadd_rn(__fadd_rn(r[0], r[1]), __fadd_rn(r[2], r[3])),
                     __fadd_rn(__fadd_rn(r[4], r[5]), __fadd_rn(r[6], r[7])));
}

// Sorted-triple insert, 5 ops (case-verified): keeps b1<=b2<=b3 smallest-3.
#define UPD3(b1v, b2v, b3v, key_)                                   \
    {                                                               \
        unsigned m_ = max(b1v, key_);                               \
        b1v = min(b1v, key_);                                       \
        unsigned m2_ = max(b2v, m_);                                \
        b2v = min(b2v, m_);                                         \
        b3v = min(b3v, m2_);                                        \
    }

// Merge two sorted triples (mine, other-lane's), keep smallest 3.
#define MRG3(b1v, b2v, b3v)                                         \
    {                                                               \
        unsigned o1_ = (unsigned)__shfl_xor((int)b1v, d);           \
        unsigned o2_ = (unsigned)__shfl_xor((int)b2v, d);           \
        unsigned o3_ = (unsigned)__shfl_xor((int)b3v, d);           \
        unsigned A_ = max(b1v, o1_);                                \
        unsigned t_ = min(b2v, o2_);                                \
        b1v = min(b1v, o1_);                                        \
        unsigned c2_ = min(A_, t_);                                 \
        b3v = min(min(max(A_, t_), max(b2v, o2_)), min(b3v, o3_));  \
        b2v = c2_;                                                  \
    }

// Approx, R24 structure with the distance math folded into the MFMA:
//  - centroids staged as f16(-2c) (exact: x2 scale is lossless in fp, no
//    overflow at |2c|<=1.7), so products accumulate -2*cross directly;
//  - C-in = {cs,cs,cs,cs}: C/D layout col=lane&15=centroid (R4-R24 proven),
//    so cs is lane-constant across the 4 regs -> MFMA emits d = cs - 2*cross.
//  Deletes fadd+fmaf per distance (R24: VALUBusy 62-66%, epilogue-bound);
//  sorted-triple insert slimmed 6->5 ops. MFMA tree-rounding (~1e-4) is far
//  inside MARGIN's ~3e-3 slack; classification/encoding unchanged (R24).
__global__ __launch_bounds__(ABLOCK) void approx_kernel(const float* __restrict__ x,
                                                        const float* __restrict__ c,
                                                        float* __restrict__ out_assign) {
    extern __shared__ char smem[];          // [0,64K): swizzled f16(-2c) | [64K,66K): scs
    float* scs = (float*)(smem + 65536);    // 512 f32: csq_approx + SHIFT

    int tid = threadIdx.x;
    const float4* src = (const float4*)c;
#pragma unroll
    for (int i = 0; i < 16; ++i) {          // 8192 f32x4 chunks = all 512 rows
        int chunk = tid + i * ABLOCK;
        int row = chunk >> 4, q = chunk & 15;
        float4 v = src[chunk];
        f16x4 h;
        h[0] = (_Float16)(-2.0f * v.x); h[1] = (_Float16)(-2.0f * v.y);
        h[2] = (_Float16)(-2.0f * v.z); h[3] = (_Float16)(-2.0f * v.w);
        int off = row * 128 + (((q >> 1) ^ (row & 7)) << 4) + (q & 1) * 8;
        *(f16x4*)(smem + off) = h;
        float s = (v.x * v.x + v.y * v.y) + (v.z * v.z + v.w * v.w);
#pragma unroll
        for (int m = 1; m < 16; m <<= 1) s += __shfl_xor(s, m);
        if (q == 0) scs[row] = s + SHIFT;
    }

    int wid = tid >> 6, lane = tid & 63;
    int lrow = lane & 15, lgrp = lane >> 4;

    for (int tile = 0; tile < TILES; ++tile) {
        __syncthreads();
        int pbase = (blockIdx.x * TILES + tile) * 256 + wid * 32;

        f16x8 a[2][2];
#pragma unroll
        for (int s = 0; s < 2; ++s)
#pragma unroll
            for (int kk = 0; kk < 2; ++kk) {
                const float4* p = (const float4*)(x + (size_t)(pbase + s * 16 + lrow) * DD
                                                  + kk * 32 + lgrp * 8);
                float4 u0 = p[0], u1 = p[1];
                f16x8 t;
                t[0] = (_Float16)u0.x; t[1] = (_Float16)u0.y;
                t[2] = (_Float16)u0.z; t[3] = (_Float16)u0.w;
                t[4] = (_Float16)u1.x; t[5] = (_Float16)u1.y;
                t[6] = (_Float16)u1.z; t[7] = (_Float16)u1.w;
                a[s][kk] = t;
            }

        unsigned b1[2][4], b2[2][4], b3[2][4];
#pragma unroll
        for (int s = 0; s < 2; ++s)
#pragma unroll
            for (int r = 0; r < 4; ++r) {
                b1[s][r] = 0xFFFFFFFFu; b2[s][r] = 0xFFFFFFFFu; b3[s][r] = 0xFFFFFFFFu;
            }

        int base0 = lrow * 128 + ((lgrp ^ (lane & 7)) << 4);
        int base1 = base0 ^ 64;
        int centv = lrow;

        f16x8 nb0 = *(const f16x8*)(smem + base0);
        f16x8 nb1 = *(const f16x8*)(smem + base1);

        for (int ct = 0; ct < 32; ++ct) {
            f16x8 bk0 = nb0, bk1 = nb1;
            base0 += 2048; base1 += 2048;
            nb0 = *(const f16x8*)(smem + base0);   // final read lands in scs: in-bounds
            nb1 = *(const f16x8*)(smem + base1);
            float cs = scs[centv];
            unsigned kv = (unsigned)centv;
            centv += 16;

            // C-in = cs (lane-constant across regs); B pre-scaled by -2 ->
            // chained pair accumulates d = cs - 2*cross directly.
            f32x4 cvec = {cs, cs, cs, cs};
            f32x4 acc0 = __builtin_amdgcn_mfma_f32_16x16x32_f16(a[0][0], bk0, cvec, 0, 0, 0);
            acc0 = __builtin_amdgcn_mfma_f32_16x16x32_f16(a[0][1], bk1, acc0, 0, 0, 0);
            f32x4 acc1 = __builtin_amdgcn_mfma_f32_16x16x32_f16(a[1][0], bk0, cvec, 0, 0, 0);
            acc1 = __builtin_amdgcn_mfma_f32_16x16x32_f16(a[1][1], bk1, acc1, 0, 0, 0);
#pragma unroll
            for (int r = 0; r < 4; ++r) {
                unsigned k0 = (__float_as_uint(acc0[r]) & 0xFFFFFE00u) | kv;
                unsigned k1 = (__float_as_uint(acc1[r]) & 0xFFFFFE00u) | kv;
                UPD3(b1[0][r], b2[0][r], b3[0][r], k0)
                UPD3(b1[1][r], b2[1][r], b3[1][r], k1)
            }
        }

#pragma unroll
        for (int d = 1; d < 16; d <<= 1) {
#pragma unroll
            for (int s = 0; s < 2; ++s)
#pragma unroll
                for (int r = 0; r < 4; ++r) {
                    MRG3(b1[s][r], b2[s][r], b3[s][r])
                }
        }

        if (lrow == 0) {
#pragma unroll
            for (int s = 0; s < 2; ++s)
#pragma unroll
                for (int r = 0; r < 4; ++r) {
                    int p = pbase + s * 16 + lgrp * 4 + r;
                    unsigned w1 = b1[s][r], w2 = b2[s][r], w3 = b3[s][r];
                    float d1 = __uint_as_float(w1 & 0xFFFFFE00u);
                    float d2 = __uint_as_float(w2 & 0xFFFFFE00u);
                    float d3 = __uint_as_float(w3 & 0xFFFFFE00u);
                    int k1 = (int)(w1 & 0x1FFu), k2 = (int)(w2 & 0x1FFu);
                    float res;
                    if (d3 - d1 <= MARGIN) res = -1.0f;
                    else if (d2 - d1 <= MARGIN) res = -(float)(2 + k1 * 1024 + k2);
                    else res = (float)k1;
                    out_assign[p] = res;
                }
        }
    }
}

// Rescore (R24, byte-identical -- measured fast): lane-parallel pair-resolve
// + wave-paired full rescan; all exact math = bit-exact np-replica op order.
__global__ __launch_bounds__(256) void rescore_kernel(const float* __restrict__ x,
                                                      const float* __restrict__ c,
                                                      float* __restrict__ out_c,
                                                      float* __restrict__ out_assign) {
    extern __shared__ char rsm[];
    float* cs = (float*)rsm;                       // [512][68] f32
    float* scsq = (float*)(rsm + KC * CSTRIDE * 4);// 512 f32, exact np csq

    int tid = threadIdx.x;
#pragma unroll
    for (int it = 0; it < 32; ++it) {
        int idx = tid + it * 256;                  // 8192 float4 chunks
        int row = idx >> 4, q = idx & 15;
        float4 v = ((const float4*)(c + row * DD))[q];
        float* d = &cs[row * CSTRIDE + q * 4];
        d[0] = v.x; d[1] = v.y; d[2] = v.z; d[3] = v.w;
    }
    if (tid < 32) {
        int j = blockIdx.x * 32 + tid;             // centroid passthrough
        ((float4*)out_c)[j] = ((const float4*)c)[j];
    }
    __syncthreads();
    scsq[tid] = csq_pairwise8(&cs[tid * CSTRIDE]);
    scsq[tid + 256] = csq_pairwise8(&cs[(tid + 256) * CSTRIDE]);
    __syncthreads();

    int wid = tid >> 6, lane = tid & 63;
    int range = blockIdx.x * 1024 + wid * 256;

    for (int seg = 0; seg < 4; ++seg) {
        int wbase = range + seg * 64;
        int myp = wbase + lane;
        float v = out_assign[myp];

        // Lane-parallel 2-candidate resolve (v <= -2).
        if (v < -1.5f) {
            int m = (int)(-v) - 2;
            int ka = m >> 10, kb = m & 1023;
            int klo = ka < kb ? ka : kb;
            int khi = ka < kb ? kb : ka;
            const float4* xp = (const float4*)(x + (size_t)myp * DD);
            const float* rlo = &cs[klo * CSTRIDE];
            const float* rhi = &cs[khi * CSTRIDE];
            float r8[8];
            float a0 = 0.f, a1 = 0.f, a2 = 0.f, a3 = 0.f;
            float c0 = 0.f, c1 = 0.f, c2 = 0.f, c3 = 0.f;
#pragma unroll
            for (int q = 0; q < 16; ++q) {
                float4 xq = xp[q];
                float4 ql = *(const float4*)(rlo + q * 4);
                float4 qh = *(const float4*)(rhi + q * 4);
                int t0 = (q & 1) * 4;
                if (q < 2) {
                    r8[t0 + 0] = __fmul_rn(xq.x, xq.x);
                    r8[t0 + 1] = __fmul_rn(xq.y, xq.y);
                    r8[t0 + 2] = __fmul_rn(xq.z, xq.z);
                    r8[t0 + 3] = __fmul_rn(xq.w, xq.w);
                } else {
                    r8[t0 + 0] = __fadd_rn(r8[t0 + 0], __fmul_rn(xq.x, xq.x));
                    r8[t0 + 1] = __fadd_rn(r8[t0 + 1], __fmul_rn(xq.y, xq.y));
                    r8[t0 + 2] = __fadd_rn(r8[t0 + 2], __fmul_rn(xq.z, xq.z));
                    r8[t0 + 3] = __fadd_rn(r8[t0 + 3], __fmul_rn(xq.w, xq.w));
                }
                a0 = __fmaf_rn(xq.x, ql.x, a0);
                a1 = __fmaf_rn(xq.y, ql.y, a1);
                a2 = __fmaf_rn(xq.z, ql.z, a2);
                a3 = __fmaf_rn(xq.w, ql.w, a3);
                c0 = __fmaf_rn(xq.x, qh.x, c0);
                c1 = __fmaf_rn(xq.y, qh.y, c1);
                c2 = __fmaf_rn(xq.z, qh.z, c2);
                c3 = __fmaf_rn(xq.w, qh.w, c3);
            }
            float x_sq = __fadd_rn(__fadd_rn(__fadd_rn(r8[0], r8[1]), __fadd_rn(r8[2], r8[3])),
                                   __fadd_rn(__fadd_rn(r8[4], r8[5]), __fadd_rn(r8[6], r8[7])));
            float dlo = __fmaf_rn(-2.0f, __fadd_rn(__fadd_rn(a0, a1), __fadd_rn(a2, a3)),
                                  __fadd_rn(x_sq, scsq[klo]));
            float dhi = __fmaf_rn(-2.0f, __fadd_rn(__fadd_rn(c0, c1), __fadd_rn(c2, c3)),
                                  __fadd_rn(x_sq, scsq[khi]));
            int ans = (dhi < dlo) ? khi : klo;     // strict <: lower index wins ties
            out_assign[myp] = (float)ans;
        }

        // Wave-paired full rescan for -1 points.
        unsigned long long mask = __ballot(v > -1.5f && v < -0.5f);
        while (mask) {
            int bit0 = __ffsll((long long)mask) - 1;
            mask &= mask - 1;
            int bit1 = bit0;
            if (mask) {
                bit1 = __ffsll((long long)mask) - 1;
                mask &= mask - 1;
            }
            int iA = wbase + bit0;
            int iB = wbase + bit1;
            const float* xA = x + (size_t)iA * DD; // wave-uniform -> s_loads
            const float* xB = x + (size_t)iB * DD;
            float xsqA = csq_pairwise8(xA);
            float xsqB = csq_pairwise8(xB);

            unsigned long long bA = ~0ull, bB = ~0ull;
#pragma unroll 1
            for (int j = 0; j < 8; ++j) {
                int k = j * 64 + lane;
                const float* crow = &cs[k * CSTRIDE];
                float a0 = 0.f, a1 = 0.f, a2 = 0.f, a3 = 0.f;
                float c0 = 0.f, c1 = 0.f, c2 = 0.f, c3 = 0.f;
#pragma unroll
                for (int q = 0; q < 16; ++q) {
                    float4 cq = *(const float4*)(crow + q * 4);
                    a0 = __fmaf_rn(xA[4 * q + 0], cq.x, a0);
                    a1 = __fmaf_rn(xA[4 * q + 1], cq.y, a1);
                    a2 = __fmaf_rn(xA[4 * q + 2], cq.z, a2);
                    a3 = __fmaf_rn(xA[4 * q + 3], cq.w, a3);
                    c0 = __fmaf_rn(xB[4 * q + 0], cq.x, c0);
                    c1 = __fmaf_rn(xB[4 * q + 1], cq.y, c1);
                    c2 = __fmaf_rn(xB[4 * q + 2], cq.z, c2);
                    c3 = __fmaf_rn(xB[4 * q + 3], cq.w, c3);
                }
                float sq = scsq[k];
                float accA = __fadd_rn(__fadd_rn(a0, a1), __fadd_rn(a2, a3));
                float accB = __fadd_rn(__fadd_rn(c0, c1), __fadd_rn(c2, c3));
                float dA = __fmaf_rn(-2.0f, accA, __fadd_rn(xsqA, sq));
                float dB = __fmaf_rn(-2.0f, accB, __fadd_rn(xsqB, sq));
                unsigned long long kA =
                    ((unsigned long long)__float_as_uint(dA) << 32) | (unsigned)k;
                unsigned long long kB =
                    ((unsigned long long)__float_as_uint(dB) << 32) | (unsigned)k;
                bA = bA < kA ? bA : kA;
                bB = bB < kB ? bB : kB;
            }
#pragma unroll
            for (int dd = 1; dd < 64; dd <<= 1) {
                unsigned hiA = (unsigned)__shfl_xor((int)(bA >> 32), dd);
                unsigned loA = (unsigned)__shfl_xor((int)(bA & 0xFFFFFFFFull), dd);
                unsigned long long oA = ((unsigned long long)hiA << 32) | loA;
                bA = bA < oA ? bA : oA;
                unsigned hiB = (unsigned)__shfl_xor((int)(bB >> 32), dd);
                unsigned loB = (unsigned)__shfl_xor((int)(bB & 0xFFFFFFFFull), dd);
                unsigned long long oB = ((unsigned long long)hiB << 32) | loB;
                bB = bB < oB ? bB : oB;
            }
            if (lane == 0) {
                out_assign[iA] = (float)(unsigned)(bA & 0xFFFFFFFFull);
                out_assign[iB] = (float)(unsigned)(bB & 0xFFFFFFFFull);
            }
        }
    }
}

extern "C" void kernel_launch(void* const* d_in, const int* in_sizes, int n_in,
                              void* d_out, int out_size, void* d_ws, size_t ws_size,
                              hipStream_t stream) {
    const float* x = (const float*)d_in[0];
    const float* c = (const float*)d_in[1];
    float* out = (float*)d_out;
    float* out_assign = out + KC * DD;

    approx_kernel<<<NPTS / (256 * TILES), ABLOCK, 67584, stream>>>(x, c, out_assign);
    rescore_kernel<<<256, 256, KC * CSTRIDE * 4 + 2048, stream>>>(x, c, out,
                                                                  out_assign);
}

// Round 26
// 79.094 us; speedup vs baseline: 1.6471x; 1.0192x over previous
//
#include <hip/hip_runtime.h>
#include <math.h>

#define NPTS 262144
#define KC 512
#define DD 64
#define MARGIN 0.02f
#define SHIFT 32.0f
#define CSTRIDE 68            // f32 row stride in LDS for rescore (272B)
#define ABLOCK 1024           // approx block: 16 waves, ONE block per CU
#define TILES 2               // 512-point tiles per approx block

typedef _Float16 f16x8 __attribute__((ext_vector_type(8)));
typedef _Float16 f16x4 __attribute__((ext_vector_type(4)));
typedef float f32x4 __attribute__((ext_vector_type(4)));

__device__ __forceinline__ float csq_pairwise8(const float* row) {
    float r[8];
#pragma unroll
    for (int t = 0; t < 8; ++t) r[t] = __fmul_rn(row[t], row[t]);
#pragma unroll
    for (int b = 1; b < 8; ++b)
#pragma unroll
        for (int t = 0; t < 8; ++t)
            r[t] = __fadd_rn(r[t], __fmul_rn(row[8 * b + t], row[8 * b + t]));
    return __fadd_rn(__fadd_rn(__fadd_rn(r[0], r[1]), __fadd_rn(r[2], r[3])),
                     __fadd_rn(__fadd_rn(r[4], r[5]), __fadd_rn(r[6], r[7])));
}

// Sorted-triple insert; b3-update shaped as min(b3, max(b2, m)) so clang can
// fuse to v_med3_u32 (valid: b2<=b3 invariant) -> 4 VALU.
#define UPD3(b1v, b2v, b3v, key_)                                   \
    {                                                               \
        unsigned m_ = max(b1v, key_);                               \
        b1v = min(b1v, key_);                                       \
        b3v = min(b3v, max(b2v, m_));                               \
        b2v = min(b2v, m_);                                         \
    }

// Merge two sorted triples (mine, other-lane's), keep smallest 3.
#define MRG3(b1v, b2v, b3v)                                         \
    {                                                               \
        unsigned o1_ = (unsigned)__shfl_xor((int)b1v, d);           \
        unsigned o2_ = (unsigned)__shfl_xor((int)b2v, d);           \
        unsigned o3_ = (unsigned)__shfl_xor((int)b3v, d);           \
        unsigned A_ = max(b1v, o1_);                                \
        unsigned t_ = min(b2v, o2_);                                \
        b1v = min(b1v, o1_);                                        \
        unsigned c2_ = min(A_, t_);                                 \
        b3v = min(min(max(A_, t_), max(b2v, o2_)), min(b3v, o3_));  \
        b2v = c2_;                                                  \
    }

// R25 approx (MFMA-folded distances, best-3) at ONE block per CU: 16 waves,
// centroid staging once per CU instead of twice (R25: 2 blocks/CU each
// staging 128KB; staging was ~15% of kernel). Same 4 waves/SIMD ceiling.
__global__ __launch_bounds__(ABLOCK) void approx_kernel(const float* __restrict__ x,
                                                        const float* __restrict__ c,
                                                        float* __restrict__ out_assign) {
    extern __shared__ char smem[];          // [0,64K): swizzled f16(-2c) | [64K,66K): scs
    float* scs = (float*)(smem + 65536);    // 512 f32: csq_approx + SHIFT

    int tid = threadIdx.x;
    const float4* src = (const float4*)c;
#pragma unroll
    for (int i = 0; i < 8; ++i) {           // 8 x 1024 = 8192 f32x4 chunks = 512 rows
        int chunk = tid + i * ABLOCK;
        int row = chunk >> 4, q = chunk & 15;
        float4 v = src[chunk];
        f16x4 h;
        h[0] = (_Float16)(-2.0f * v.x); h[1] = (_Float16)(-2.0f * v.y);
        h[2] = (_Float16)(-2.0f * v.z); h[3] = (_Float16)(-2.0f * v.w);
        int off = row * 128 + (((q >> 1) ^ (row & 7)) << 4) + (q & 1) * 8;
        *(f16x4*)(smem + off) = h;
        float s = (v.x * v.x + v.y * v.y) + (v.z * v.z + v.w * v.w);
#pragma unroll
        for (int m = 1; m < 16; m <<= 1) s += __shfl_xor(s, m);
        if (q == 0) scs[row] = s + SHIFT;   // single writer per row
    }

    int wid = tid >> 6, lane = tid & 63;
    int lrow = lane & 15, lgrp = lane >> 4;

    for (int tile = 0; tile < TILES; ++tile) {
        __syncthreads();
        int pbase = (blockIdx.x * TILES + tile) * 512 + wid * 32;

        f16x8 a[2][2];
#pragma unroll
        for (int s = 0; s < 2; ++s)
#pragma unroll
            for (int kk = 0; kk < 2; ++kk) {
                const float4* p = (const float4*)(x + (size_t)(pbase + s * 16 + lrow) * DD
                                                  + kk * 32 + lgrp * 8);
                float4 u0 = p[0], u1 = p[1];
                f16x8 t;
                t[0] = (_Float16)u0.x; t[1] = (_Float16)u0.y;
                t[2] = (_Float16)u0.z; t[3] = (_Float16)u0.w;
                t[4] = (_Float16)u1.x; t[5] = (_Float16)u1.y;
                t[6] = (_Float16)u1.z; t[7] = (_Float16)u1.w;
                a[s][kk] = t;
            }

        unsigned b1[2][4], b2[2][4], b3[2][4];
#pragma unroll
        for (int s = 0; s < 2; ++s)
#pragma unroll
            for (int r = 0; r < 4; ++r) {
                b1[s][r] = 0xFFFFFFFFu; b2[s][r] = 0xFFFFFFFFu; b3[s][r] = 0xFFFFFFFFu;
            }

        int base0 = lrow * 128 + ((lgrp ^ (lane & 7)) << 4);
        int base1 = base0 ^ 64;
        int centv = lrow;

        f16x8 nb0 = *(const f16x8*)(smem + base0);
        f16x8 nb1 = *(const f16x8*)(smem + base1);

        for (int ct = 0; ct < 32; ++ct) {
            f16x8 bk0 = nb0, bk1 = nb1;
            base0 += 2048; base1 += 2048;
            nb0 = *(const f16x8*)(smem + base0);   // final read lands in scs: in-bounds
            nb1 = *(const f16x8*)(smem + base1);
            float cs = scs[centv];
            unsigned kv = (unsigned)centv;
            centv += 16;

            // C-in = cs (lane-constant across regs, C/D col=lane&15 proven);
            // B pre-scaled by -2 -> chained pair emits d = cs - 2*cross.
            f32x4 cvec = {cs, cs, cs, cs};
            f32x4 acc0 = __builtin_amdgcn_mfma_f32_16x16x32_f16(a[0][0], bk0, cvec, 0, 0, 0);
            acc0 = __builtin_amdgcn_mfma_f32_16x16x32_f16(a[0][1], bk1, acc0, 0, 0, 0);
            f32x4 acc1 = __builtin_amdgcn_mfma_f32_16x16x32_f16(a[1][0], bk0, cvec, 0, 0, 0);
            acc1 = __builtin_amdgcn_mfma_f32_16x16x32_f16(a[1][1], bk1, acc1, 0, 0, 0);
#pragma unroll
            for (int r = 0; r < 4; ++r) {
                unsigned k0 = (__float_as_uint(acc0[r]) & 0xFFFFFE00u) | kv;
                unsigned k1 = (__float_as_uint(acc1[r]) & 0xFFFFFE00u) | kv;
                UPD3(b1[0][r], b2[0][r], b3[0][r], k0)
                UPD3(b1[1][r], b2[1][r], b3[1][r], k1)
            }
        }

#pragma unroll
        for (int d = 1; d < 16; d <<= 1) {
#pragma unroll
            for (int s = 0; s < 2; ++s)
#pragma unroll
                for (int r = 0; r < 4; ++r) {
                    MRG3(b1[s][r], b2[s][r], b3[s][r])
                }
        }

        if (lrow == 0) {
#pragma unroll
            for (int s = 0; s < 2; ++s)
#pragma unroll
                for (int r = 0; r < 4; ++r) {
                    int p = pbase + s * 16 + lgrp * 4 + r;
                    unsigned w1 = b1[s][r], w2 = b2[s][r], w3 = b3[s][r];
                    float d1 = __uint_as_float(w1 & 0xFFFFFE00u);
                    float d2 = __uint_as_float(w2 & 0xFFFFFE00u);
                    float d3 = __uint_as_float(w3 & 0xFFFFFE00u);
                    int k1 = (int)(w1 & 0x1FFu), k2 = (int)(w2 & 0x1FFu);
                    float res;
                    if (d3 - d1 <= MARGIN) res = -1.0f;
                    else if (d2 - d1 <= MARGIN) res = -(float)(2 + k1 * 1024 + k2);
                    else res = (float)k1;
                    out_assign[p] = res;
                }
        }
    }
}

// Rescore (R24/R25, byte-identical): lane-parallel pair-resolve + wave-paired
// full rescan; all exact math = bit-exact np-replica op order.
__global__ __launch_bounds__(256) void rescore_kernel(const float* __restrict__ x,
                                                      const float* __restrict__ c,
                                                      float* __restrict__ out_c,
                                                      float* __restrict__ out_assign) {
    extern __shared__ char rsm[];
    float* cs = (float*)rsm;                       // [512][68] f32
    float* scsq = (float*)(rsm + KC * CSTRIDE * 4);// 512 f32, exact np csq

    int tid = threadIdx.x;
#pragma unroll
    for (int it = 0; it < 32; ++it) {
        int idx = tid + it * 256;                  // 8192 float4 chunks
        int row = idx >> 4, q = idx & 15;
        float4 v = ((const float4*)(c + row * DD))[q];
        float* d = &cs[row * CSTRIDE + q * 4];
        d[0] = v.x; d[1] = v.y; d[2] = v.z; d[3] = v.w;
    }
    if (tid < 32) {
        int j = blockIdx.x * 32 + tid;             // centroid passthrough
        ((float4*)out_c)[j] = ((const float4*)c)[j];
    }
    __syncthreads();
    scsq[tid] = csq_pairwise8(&cs[tid * CSTRIDE]);
    scsq[tid + 256] = csq_pairwise8(&cs[(tid + 256) * CSTRIDE]);
    __syncthreads();

    int wid = tid >> 6, lane = tid & 63;
    int range = blockIdx.x * 1024 + wid * 256;

    for (int seg = 0; seg < 4; ++seg) {
        int wbase = range + seg * 64;
        int myp = wbase + lane;
        float v = out_assign[myp];

        // Lane-parallel 2-candidate resolve (v <= -2).
        if (v < -1.5f) {
            int m = (int)(-v) - 2;
            int ka = m >> 10, kb = m & 1023;
            int klo = ka < kb ? ka : kb;
            int khi = ka < kb ? kb : ka;
            const float4* xp = (const float4*)(x + (size_t)myp * DD);
            const float* rlo = &cs[klo * CSTRIDE];
            const float* rhi = &cs[khi * CSTRIDE];
            float r8[8];
            float a0 = 0.f, a1 = 0.f, a2 = 0.f, a3 = 0.f;
            float c0 = 0.f, c1 = 0.f, c2 = 0.f, c3 = 0.f;
#pragma unroll
            for (int q = 0; q < 16; ++q) {
                float4 xq = xp[q];
                float4 ql = *(const float4*)(rlo + q * 4);
                float4 qh = *(const float4*)(rhi + q * 4);
                int t0 = (q & 1) * 4;
                if (q < 2) {
                    r8[t0 + 0] = __fmul_rn(xq.x, xq.x);
                    r8[t0 + 1] = __fmul_rn(xq.y, xq.y);
                    r8[t0 + 2] = __fmul_rn(xq.z, xq.z);
                    r8[t0 + 3] = __fmul_rn(xq.w, xq.w);
                } else {
                    r8[t0 + 0] = __fadd_rn(r8[t0 + 0], __fmul_rn(xq.x, xq.x));
                    r8[t0 + 1] = __fadd_rn(r8[t0 + 1], __fmul_rn(xq.y, xq.y));
                    r8[t0 + 2] = __fadd_rn(r8[t0 + 2], __fmul_rn(xq.z, xq.z));
                    r8[t0 + 3] = __fadd_rn(r8[t0 + 3], __fmul_rn(xq.w, xq.w));
                }
                a0 = __fmaf_rn(xq.x, ql.x, a0);
                a1 = __fmaf_rn(xq.y, ql.y, a1);
                a2 = __fmaf_rn(xq.z, ql.z, a2);
                a3 = __fmaf_rn(xq.w, ql.w, a3);
                c0 = __fmaf_rn(xq.x, qh.x, c0);
                c1 = __fmaf_rn(xq.y, qh.y, c1);
                c2 = __fmaf_rn(xq.z, qh.z, c2);
                c3 = __fmaf_rn(xq.w, qh.w, c3);
            }
            float x_sq = __fadd_rn(__fadd_rn(__fadd_rn(r8[0], r8[1]), __fadd_rn(r8[2], r8[3])),
                                   __fadd_rn(__fadd_rn(r8[4], r8[5]), __fadd_rn(r8[6], r8[7])));
            float dlo = __fmaf_rn(-2.0f, __fadd_rn(__fadd_rn(a0, a1), __fadd_rn(a2, a3)),
                                  __fadd_rn(x_sq, scsq[klo]));
            float dhi = __fmaf_rn(-2.0f, __fadd_rn(__fadd_rn(c0, c1), __fadd_rn(c2, c3)),
                                  __fadd_rn(x_sq, scsq[khi]));
            int ans = (dhi < dlo) ? khi : klo;     // strict <: lower index wins ties
            out_assign[myp] = (float)ans;
        }

        // Wave-paired full rescan for -1 points.
        unsigned long long mask = __ballot(v > -1.5f && v < -0.5f);
        while (mask) {
            int bit0 = __ffsll((long long)mask) - 1;
            mask &= mask - 1;
            int bit1 = bit0;
            if (mask) {
                bit1 = __ffsll((long long)mask) - 1;
                mask &= mask - 1;
            }
            int iA = wbase + bit0;
            int iB = wbase + bit1;
            const float* xA = x + (size_t)iA * DD; // wave-uniform -> s_loads
            const float* xB = x + (size_t)iB * DD;
            float xsqA = csq_pairwise8(xA);
            float xsqB = csq_pairwise8(xB);

            unsigned long long bA = ~0ull, bB = ~0ull;
#pragma unroll 1
            for (int j = 0; j < 8; ++j) {
                int k = j * 64 + lane;
                const float* crow = &cs[k * CSTRIDE];
                float a0 = 0.f, a1 = 0.f, a2 = 0.f, a3 = 0.f;
                float c0 = 0.f, c1 = 0.f, c2 = 0.f, c3 = 0.f;
#pragma unroll
                for (int q = 0; q < 16; ++q) {
                    float4 cq = *(const float4*)(crow + q * 4);
                    a0 = __fmaf_rn(xA[4 * q + 0], cq.x, a0);
                    a1 = __fmaf_rn(xA[4 * q + 1], cq.y, a1);
                    a2 = __fmaf_rn(xA[4 * q + 2], cq.z, a2);
                    a3 = __fmaf_rn(xA[4 * q + 3], cq.w, a3);
                    c0 = __fmaf_rn(xB[4 * q + 0], cq.x, c0);
                    c1 = __fmaf_rn(xB[4 * q + 1], cq.y, c1);
                    c2 = __fmaf_rn(xB[4 * q + 2], cq.z, c2);
                    c3 = __fmaf_rn(xB[4 * q + 3], cq.w, c3);
                }
                float sq = scsq[k];
                float accA = __fadd_rn(__fadd_rn(a0, a1), __fadd_rn(a2, a3));
                float accB = __fadd_rn(__fadd_rn(c0, c1), __fadd_rn(c2, c3));
                float dA = __fmaf_rn(-2.0f, accA, __fadd_rn(xsqA, sq));
                float dB = __fmaf_rn(-2.0f, accB, __fadd_rn(xsqB, sq));
                unsigned long long kA =
                    ((unsigned long long)__float_as_uint(dA) << 32) | (unsigned)k;
                unsigned long long kB =
                    ((unsigned long long)__float_as_uint(dB) << 32) | (unsigned)k;
                bA = bA < kA ? bA : kA;
                bB = bB < kB ? bB : kB;
            }
#pragma unroll
            for (int dd = 1; dd < 64; dd <<= 1) {
                unsigned hiA = (unsigned)__shfl_xor((int)(bA >> 32), dd);
                unsigned loA = (unsigned)__shfl_xor((int)(bA & 0xFFFFFFFFull), dd);
                unsigned long long oA = ((unsigned long long)hiA << 32) | loA;
                bA = bA < oA ? bA : oA;
                unsigned hiB = (unsigned)__shfl_xor((int)(bB >> 32), dd);
                unsigned loB = (unsigned)__shfl_xor((int)(bB & 0xFFFFFFFFull), dd);
                unsigned long long oB = ((unsigned long long)hiB << 32) | loB;
                bB = bB < oB ? bB : oB;
            }
            if (lane == 0) {
                out_assign[iA] = (float)(unsigned)(bA & 0xFFFFFFFFull);
                out_assign[iB] = (float)(unsigned)(bB & 0xFFFFFFFFull);
            }
        }
    }
}

extern "C" void kernel_launch(void* const* d_in, const int* in_sizes, int n_in,
                              void* d_out, int out_size, void* d_ws, size_t ws_size,
                              hipStream_t stream) {
    const float* x = (const float*)d_in[0];
    const float* c = (const float*)d_in[1];
    float* out = (float*)d_out;
    float* out_assign = out + KC * DD;

    approx_kernel<<<NPTS / (512 * TILES), ABLOCK, 67584, stream>>>(x, c, out_assign);
    rescore_kernel<<<256, 256, KC * CSTRIDE * 4 + 2048, stream>>>(x, c, out,
                                                                  out_assign);
}

// Round 27
// 78.618 us; speedup vs baseline: 1.6570x; 1.0061x over previous
//
#include <hip/hip_runtime.h>
#include <math.h>

#define NPTS 262144
#define KC 512
#define DD 64
#define MARGIN 0.02f
#define SHIFT 32.0f
#define CSTRIDE 68            // f32 row stride in LDS for rescore (272B)
#define ABLOCK 1024           // approx block: 16 waves, ONE block per CU
#define TILES 2               // 512-point tiles per approx block

typedef _Float16 f16x8 __attribute__((ext_vector_type(8)));
typedef _Float16 f16x4 __attribute__((ext_vector_type(4)));
typedef float f32x4 __attribute__((ext_vector_type(4)));

__device__ __forceinline__ float csq_pairwise8(const float* row) {
    float r[8];
#pragma unroll
    for (int t = 0; t < 8; ++t) r[t] = __fmul_rn(row[t], row[t]);
#pragma unroll
    for (int b = 1; b < 8; ++b)
#pragma unroll
        for (int t = 0; t < 8; ++t)
            r[t] = __fadd_rn(r[t], __fmul_rn(row[8 * b + t], row[8 * b + t]));
    return __fadd_rn(__fadd_rn(__fadd_rn(r[0], r[1]), __fadd_rn(r[2], r[3])),
                     __fadd_rn(__fadd_rn(r[4], r[5]), __fadd_rn(r[6], r[7])));
}

// Sorted-triple insert (4 VALU; b3 as min(b3, max(b2, m)) -> v_med3-fusable).
#define UPD3(b1v, b2v, b3v, key_)                                   \
    {                                                               \
        unsigned m_ = max(b1v, key_);                               \
        b1v = min(b1v, key_);                                       \
        b3v = min(b3v, max(b2v, m_));                               \
        b2v = min(b2v, m_);                                         \
    }

// Merge two sorted triples (mine, other-lane's), keep smallest 3.
#define MRG3(b1v, b2v, b3v)                                         \
    {                                                               \
        unsigned o1_ = (unsigned)__shfl_xor((int)b1v, d);           \
        unsigned o2_ = (unsigned)__shfl_xor((int)b2v, d);           \
        unsigned o3_ = (unsigned)__shfl_xor((int)b3v, d);           \
        unsigned A_ = max(b1v, o1_);                                \
        unsigned t_ = min(b2v, o2_);                                \
        b1v = min(b1v, o1_);                                        \
        unsigned c2_ = min(A_, t_);                                 \
        b3v = min(min(max(A_, t_), max(b2v, o2_)), min(b3v, o3_));  \
        b2v = c2_;                                                  \
    }

// One MFMA-folded distance step for one B-pair (bq0,bq1) at centroid centv_.
#define CTSTEP(bq0, bq1, centv_)                                              \
    {                                                                         \
        float cs_ = scs[centv_];                                              \
        unsigned kv_ = (unsigned)(centv_);                                    \
        f32x4 cvec_ = {cs_, cs_, cs_, cs_};                                   \
        f32x4 acc0_ = __builtin_amdgcn_mfma_f32_16x16x32_f16(a[0][0], bq0, cvec_, 0, 0, 0); \
        acc0_ = __builtin_amdgcn_mfma_f32_16x16x32_f16(a[0][1], bq1, acc0_, 0, 0, 0);       \
        f32x4 acc1_ = __builtin_amdgcn_mfma_f32_16x16x32_f16(a[1][0], bq0, cvec_, 0, 0, 0); \
        acc1_ = __builtin_amdgcn_mfma_f32_16x16x32_f16(a[1][1], bq1, acc1_, 0, 0, 0);       \
        _Pragma("unroll")                                                     \
        for (int r = 0; r < 4; ++r) {                                         \
            unsigned k0_ = (__float_as_uint(acc0_[r]) & 0xFFFFFE00u) | kv_;   \
            unsigned k1_ = (__float_as_uint(acc1_[r]) & 0xFFFFFE00u) | kv_;   \
            UPD3(b1[0][r], b2[0][r], b3[0][r], k0_)                           \
            UPD3(b1[1][r], b2[1][r], b3[1][r], k1_)                           \
        }                                                                     \
    }

// R26 approx with ping-pong unroll-2 ct-loop: prefetch lands directly in the
// consuming registers (R26 carried 16 v_mov/iter from the R20 double-buffer
// copies -- ~20% of the VALU stream now that the epilogue is slim). Math
// content/order per ct unchanged. Final prefetch reads up to byte 67648 ->
// dynamic LDS 69632 (still 1 block/CU).
__global__ __launch_bounds__(ABLOCK) void approx_kernel(const float* __restrict__ x,
                                                        const float* __restrict__ c,
                                                        float* __restrict__ out_assign) {
    extern __shared__ char smem[];          // [0,64K): swizzled f16(-2c) | [64K,66K): scs
    float* scs = (float*)(smem + 65536);    // 512 f32: csq_approx + SHIFT

    int tid = threadIdx.x;
    const float4* src = (const float4*)c;
#pragma unroll
    for (int i = 0; i < 8; ++i) {           // 8 x 1024 = 8192 f32x4 chunks = 512 rows
        int chunk = tid + i * ABLOCK;
        int row = chunk >> 4, q = chunk & 15;
        float4 v = src[chunk];
        f16x4 h;
        h[0] = (_Float16)(-2.0f * v.x); h[1] = (_Float16)(-2.0f * v.y);
        h[2] = (_Float16)(-2.0f * v.z); h[3] = (_Float16)(-2.0f * v.w);
        int off = row * 128 + (((q >> 1) ^ (row & 7)) << 4) + (q & 1) * 8;
        *(f16x4*)(smem + off) = h;
        float s = (v.x * v.x + v.y * v.y) + (v.z * v.z + v.w * v.w);
#pragma unroll
        for (int m = 1; m < 16; m <<= 1) s += __shfl_xor(s, m);
        if (q == 0) scs[row] = s + SHIFT;   // single writer per row
    }

    int wid = tid >> 6, lane = tid & 63;
    int lrow = lane & 15, lgrp = lane >> 4;

    for (int tile = 0; tile < TILES; ++tile) {
        __syncthreads();
        int pbase = (blockIdx.x * TILES + tile) * 512 + wid * 32;

        f16x8 a[2][2];
#pragma unroll
        for (int s = 0; s < 2; ++s)
#pragma unroll
            for (int kk = 0; kk < 2; ++kk) {
                const float4* p = (const float4*)(x + (size_t)(pbase + s * 16 + lrow) * DD
                                                  + kk * 32 + lgrp * 8);
                float4 u0 = p[0], u1 = p[1];
                f16x8 t;
                t[0] = (_Float16)u0.x; t[1] = (_Float16)u0.y;
                t[2] = (_Float16)u0.z; t[3] = (_Float16)u0.w;
                t[4] = (_Float16)u1.x; t[5] = (_Float16)u1.y;
                t[6] = (_Float16)u1.z; t[7] = (_Float16)u1.w;
                a[s][kk] = t;
            }

        unsigned b1[2][4], b2[2][4], b3[2][4];
#pragma unroll
        for (int s = 0; s < 2; ++s)
#pragma unroll
            for (int r = 0; r < 4; ++r) {
                b1[s][r] = 0xFFFFFFFFu; b2[s][r] = 0xFFFFFFFFu; b3[s][r] = 0xFFFFFFFFu;
            }

        int base0 = lrow * 128 + ((lgrp ^ (lane & 7)) << 4);
        int base1 = base0 ^ 64;
        int centv = lrow;

        // Ping-pong: pa = current-even, pb = current-odd; prefetch writes the
        // set consumed two half-steps later (no register copies).
        f16x8 pa0 = *(const f16x8*)(smem + base0);
        f16x8 pa1 = *(const f16x8*)(smem + base1);
        f16x8 pb0 = *(const f16x8*)(smem + base0 + 2048);
        f16x8 pb1 = *(const f16x8*)(smem + base1 + 2048);

        for (int ct = 0; ct < 32; ct += 2) {
            base0 += 4096; base1 += 4096;
            // even step: consume pa, prefetch pa for ct+2
            CTSTEP(pa0, pa1, centv)
            pa0 = *(const f16x8*)(smem + base0);        // last read <= 67648: in-bounds
            pa1 = *(const f16x8*)(smem + base1);
            // odd step: consume pb, prefetch pb for ct+3
            CTSTEP(pb0, pb1, centv + 16)
            pb0 = *(const f16x8*)(smem + base0 + 2048);
            pb1 = *(const f16x8*)(smem + base1 + 2048);
            centv += 32;
        }

#pragma unroll
        for (int d = 1; d < 16; d <<= 1) {
#pragma unroll
            for (int s = 0; s < 2; ++s)
#pragma unroll
                for (int r = 0; r < 4; ++r) {
                    MRG3(b1[s][r], b2[s][r], b3[s][r])
                }
        }

        if (lrow == 0) {
#pragma unroll
            for (int s = 0; s < 2; ++s)
#pragma unroll
                for (int r = 0; r < 4; ++r) {
                    int p = pbase + s * 16 + lgrp * 4 + r;
                    unsigned w1 = b1[s][r], w2 = b2[s][r], w3 = b3[s][r];
                    float d1 = __uint_as_float(w1 & 0xFFFFFE00u);
                    float d2 = __uint_as_float(w2 & 0xFFFFFE00u);
                    float d3 = __uint_as_float(w3 & 0xFFFFFE00u);
                    int k1 = (int)(w1 & 0x1FFu), k2 = (int)(w2 & 0x1FFu);
                    float res;
                    if (d3 - d1 <= MARGIN) res = -1.0f;
                    else if (d2 - d1 <= MARGIN) res = -(float)(2 + k1 * 1024 + k2);
                    else res = (float)k1;
                    out_assign[p] = res;
                }
        }
    }
}

// Rescore (R24-R26, byte-identical): lane-parallel pair-resolve + wave-paired
// full rescan; all exact math = bit-exact np-replica op order.
__global__ __launch_bounds__(256) void rescore_kernel(const float* __restrict__ x,
                                                      const float* __restrict__ c,
                                                      float* __restrict__ out_c,
                                                      float* __restrict__ out_assign) {
    extern __shared__ char rsm[];
    float* cs = (float*)rsm;                       // [512][68] f32
    float* scsq = (float*)(rsm + KC * CSTRIDE * 4);// 512 f32, exact np csq

    int tid = threadIdx.x;
#pragma unroll
    for (int it = 0; it < 32; ++it) {
        int idx = tid + it * 256;                  // 8192 float4 chunks
        int row = idx >> 4, q = idx & 15;
        float4 v = ((const float4*)(c + row * DD))[q];
        float* d = &cs[row * CSTRIDE + q * 4];
        d[0] = v.x; d[1] = v.y; d[2] = v.z; d[3] = v.w;
    }
    if (tid < 32) {
        int j = blockIdx.x * 32 + tid;             // centroid passthrough
        ((float4*)out_c)[j] = ((const float4*)c)[j];
    }
    __syncthreads();
    scsq[tid] = csq_pairwise8(&cs[tid * CSTRIDE]);
    scsq[tid + 256] = csq_pairwise8(&cs[(tid + 256) * CSTRIDE]);
    __syncthreads();

    int wid = tid >> 6, lane = tid & 63;
    int range = blockIdx.x * 1024 + wid * 256;

    for (int seg = 0; seg < 4; ++seg) {
        int wbase = range + seg * 64;
        int myp = wbase + lane;
        float v = out_assign[myp];

        // Lane-parallel 2-candidate resolve (v <= -2).
        if (v < -1.5f) {
            int m = (int)(-v) - 2;
            int ka = m >> 10, kb = m & 1023;
            int klo = ka < kb ? ka : kb;
            int khi = ka < kb ? kb : ka;
            const float4* xp = (const float4*)(x + (size_t)myp * DD);
            const float* rlo = &cs[klo * CSTRIDE];
            const float* rhi = &cs[khi * CSTRIDE];
            float r8[8];
            float a0 = 0.f, a1 = 0.f, a2 = 0.f, a3 = 0.f;
            float c0 = 0.f, c1 = 0.f, c2 = 0.f, c3 = 0.f;
#pragma unroll
            for (int q = 0; q < 16; ++q) {
                float4 xq = xp[q];
                float4 ql = *(const float4*)(rlo + q * 4);
                float4 qh = *(const float4*)(rhi + q * 4);
                int t0 = (q & 1) * 4;
                if (q < 2) {
                    r8[t0 + 0] = __fmul_rn(xq.x, xq.x);
                    r8[t0 + 1] = __fmul_rn(xq.y, xq.y);
                    r8[t0 + 2] = __fmul_rn(xq.z, xq.z);
                    r8[t0 + 3] = __fmul_rn(xq.w, xq.w);
                } else {
                    r8[t0 + 0] = __fadd_rn(r8[t0 + 0], __fmul_rn(xq.x, xq.x));
                    r8[t0 + 1] = __fadd_rn(r8[t0 + 1], __fmul_rn(xq.y, xq.y));
                    r8[t0 + 2] = __fadd_rn(r8[t0 + 2], __fmul_rn(xq.z, xq.z));
                    r8[t0 + 3] = __fadd_rn(r8[t0 + 3], __fmul_rn(xq.w, xq.w));
                }
                a0 = __fmaf_rn(xq.x, ql.x, a0);
                a1 = __fmaf_rn(xq.y, ql.y, a1);
                a2 = __fmaf_rn(xq.z, ql.z, a2);
                a3 = __fmaf_rn(xq.w, ql.w, a3);
                c0 = __fmaf_rn(xq.x, qh.x, c0);
                c1 = __fmaf_rn(xq.y, qh.y, c1);
                c2 = __fmaf_rn(xq.z, qh.z, c2);
                c3 = __fmaf_rn(xq.w, qh.w, c3);
            }
            float x_sq = __fadd_rn(__fadd_rn(__fadd_rn(r8[0], r8[1]), __fadd_rn(r8[2], r8[3])),
                                   __fadd_rn(__fadd_rn(r8[4], r8[5]), __fadd_rn(r8[6], r8[7])));
            float dlo = __fmaf_rn(-2.0f, __fadd_rn(__fadd_rn(a0, a1), __fadd_rn(a2, a3)),
                                  __fadd_rn(x_sq, scsq[klo]));
            float dhi = __fmaf_rn(-2.0f, __fadd_rn(__fadd_rn(c0, c1), __fadd_rn(c2, c3)),
                                  __fadd_rn(x_sq, scsq[khi]));
            int ans = (dhi < dlo) ? khi : klo;     // strict <: lower index wins ties
            out_assign[myp] = (float)ans;
        }

        // Wave-paired full rescan for -1 points.
        unsigned long long mask = __ballot(v > -1.5f && v < -0.5f);
        while (mask) {
            int bit0 = __ffsll((long long)mask) - 1;
            mask &= mask - 1;
            int bit1 = bit0;
            if (mask) {
                bit1 = __ffsll((long long)mask) - 1;
                mask &= mask - 1;
            }
            int iA = wbase + bit0;
            int iB = wbase + bit1;
            const float* xA = x + (size_t)iA * DD; // wave-uniform -> s_loads
            const float* xB = x + (size_t)iB * DD;
            float xsqA = csq_pairwise8(xA);
            float xsqB = csq_pairwise8(xB);

            unsigned long long bA = ~0ull, bB = ~0ull;
#pragma unroll 1
            for (int j = 0; j < 8; ++j) {
                int k = j * 64 + lane;
                const float* crow = &cs[k * CSTRIDE];
                float a0 = 0.f, a1 = 0.f, a2 = 0.f, a3 = 0.f;
                float c0 = 0.f, c1 = 0.f, c2 = 0.f, c3 = 0.f;
#pragma unroll
                for (int q = 0; q < 16; ++q) {
                    float4 cq = *(const float4*)(crow + q * 4);
                    a0 = __fmaf_rn(xA[4 * q + 0], cq.x, a0);
                    a1 = __fmaf_rn(xA[4 * q + 1], cq.y, a1);
                    a2 = __fmaf_rn(xA[4 * q + 2], cq.z, a2);
                    a3 = __fmaf_rn(xA[4 * q + 3], cq.w, a3);
                    c0 = __fmaf_rn(xB[4 * q + 0], cq.x, c0);
                    c1 = __fmaf_rn(xB[4 * q + 1], cq.y, c1);
                    c2 = __fmaf_rn(xB[4 * q + 2], cq.z, c2);
                    c3 = __fmaf_rn(xB[4 * q + 3], cq.w, c3);
                }
                float sq = scsq[k];
                float accA = __fadd_rn(__fadd_rn(a0, a1), __fadd_rn(a2, a3));
                float accB = __fadd_rn(__fadd_rn(c0, c1), __fadd_rn(c2, c3));
                float dA = __fmaf_rn(-2.0f, accA, __fadd_rn(xsqA, sq));
                float dB = __fmaf_rn(-2.0f, accB, __fadd_rn(xsqB, sq));
                unsigned long long kA =
                    ((unsigned long long)__float_as_uint(dA) << 32) | (unsigned)k;
                unsigned long long kB =
                    ((unsigned long long)__float_as_uint(dB) << 32) | (unsigned)k;
                bA = bA < kA ? bA : kA;
                bB = bB < kB ? bB : kB;
            }
#pragma unroll
            for (int dd = 1; dd < 64; dd <<= 1) {
                unsigned hiA = (unsigned)__shfl_xor((int)(bA >> 32), dd);
                unsigned loA = (unsigned)__shfl_xor((int)(bA & 0xFFFFFFFFull), dd);
                unsigned long long oA = ((unsigned long long)hiA << 32) | loA;
                bA = bA < oA ? bA : oA;
                unsigned hiB = (unsigned)__shfl_xor((int)(bB >> 32), dd);
                unsigned loB = (unsigned)__shfl_xor((int)(bB & 0xFFFFFFFFull), dd);
                unsigned long long oB = ((unsigned long long)hiB << 32) | loB;
                bB = bB < oB ? bB : oB;
            }
            if (lane == 0) {
                out_assign[iA] = (float)(unsigned)(bA & 0xFFFFFFFFull);
                out_assign[iB] = (float)(unsigned)(bB & 0xFFFFFFFFull);
            }
        }
    }
}

extern "C" void kernel_launch(void* const* d_in, const int* in_sizes, int n_in,
                              void* d_out, int out_size, void* d_ws, size_t ws_size,
                              hipStream_t stream) {
    const float* x = (const float*)d_in[0];
    const float* c = (const float*)d_in[1];
    float* out = (float*)d_out;
    float* out_assign = out + KC * DD;

    approx_kernel<<<NPTS / (512 * TILES), ABLOCK, 69632, stream>>>(x, c, out_assign);
    rescore_kernel<<<256, 256, KC * CSTRIDE * 4 + 2048, stream>>>(x, c, out,
                                                                  out_assign);
}